// Round 3
// baseline (1263.361 us; speedup 1.0000x reference)
//
#include <hip/hip_runtime.h>
#include <stdint.h>

#define DIMC 1024
#define TOK  4096      // B*T
#define SEGN 8
#define SD   128
#define NE   16
#define RSEG 32768     // TOK*SEGN
#define HSH  4096
#define HR   512

#define BM 128
#define BN 128
#define BK 32

using bf16x8 = __attribute__((ext_vector_type(8))) __bf16;
using f32x4  = __attribute__((ext_vector_type(4))) float;

__device__ __forceinline__ unsigned short f2bf(float f) {
  unsigned int x = __builtin_bit_cast(unsigned int, f);
  unsigned int r = (x + 0x7fffu + ((x >> 16) & 1u)) >> 16;
  return (unsigned short)r;
}

__device__ __forceinline__ float gelu_f(float x) {
  // jax.nn.gelu approximate=True: 0.5x(1+tanh(0.79788456(x+0.044715x^3)))
  //                             = x * sigmoid(1.5957691(x+0.044715x^3))
  float u2 = -1.5957691216057308f * (x + 0.044715f * x * x * x);
  return x / (1.f + __expf(u2));
}

#define GLDS(gp, lp) __builtin_amdgcn_global_load_lds( \
    (const __attribute__((address_space(1))) void*)(gp), \
    (__attribute__((address_space(3))) void*)(lp), 16, 0, 0)

// C[M,N] = A[M,K] @ BT[N,K]^T  (A,BT bf16 row-major; fp32 accum)
// EPI 0: Cb = bf16(gelu(acc + bias[n]))
// EPI 1: Cf = acc + bias[n]
// EPI 2: Cf += w_e(row, expert) * (acc + bias[n])
template <int EPI>
__global__ __launch_bounds__(256) void gemm_bt(
    const unsigned short* __restrict__ A,
    const unsigned short* __restrict__ BT,
    const float* __restrict__ bias,
    float* __restrict__ Cf,
    unsigned short* __restrict__ Cb,
    int M, int N, int K,
    int expert,
    const int* __restrict__ idx0, const int* __restrict__ idx1,
    const float* __restrict__ w0, const float* __restrict__ w1)
{
  __shared__ unsigned short As[BM * BK];
  __shared__ unsigned short Bs[BN * BK];
  const int t = threadIdx.x;
  const int w = t >> 6, l = t & 63;
  const long mBase = (long)blockIdx.y * BM;
  const long nBase = (long)blockIdx.x * BN;
  const int wm = w >> 1, wn = w & 1;

  // staging: wave w covers rows [16w,16w+16) and [64+16w, ...); lane l: row +l/4, 16B chunk (l&3)
  const int rowc = w * 16 + (l >> 2);
  const int colE = (l & 3) * 8;
  const unsigned short* gA0 = A + (mBase + rowc) * (long)K + colE;
  const unsigned short* gA1 = A + (mBase + 64 + rowc) * (long)K + colE;
  const unsigned short* gB0 = BT + (nBase + rowc) * (long)K + colE;
  const unsigned short* gB1 = BT + (nBase + 64 + rowc) * (long)K + colE;
  unsigned short* lA0 = &As[(w * 16) * BK];
  unsigned short* lA1 = &As[(64 + w * 16) * BK];
  unsigned short* lB0 = &Bs[(w * 16) * BK];
  unsigned short* lB1 = &Bs[(64 + w * 16) * BK];

  f32x4 acc[4][4] = {};

  const int ar = l & 15;        // A row / B col within fragment
  const int ak = (l >> 4) * 8;  // k-offset within fragment

  for (int kt = 0; kt < K; kt += BK) {
    GLDS(gA0 + kt, lA0);
    GLDS(gA1 + kt, lA1);
    GLDS(gB0 + kt, lB0);
    GLDS(gB1 + kt, lB1);
    __syncthreads();  // compiler emits vmcnt(0) drain before s_barrier
    bf16x8 av[4], bv[4];
#pragma unroll
    for (int f = 0; f < 4; ++f)
      av[f] = *(const bf16x8*)&As[(wm * 64 + f * 16 + ar) * BK + ak];
#pragma unroll
    for (int g = 0; g < 4; ++g)
      bv[g] = *(const bf16x8*)&Bs[(wn * 64 + g * 16 + ar) * BK + ak];
#pragma unroll
    for (int f = 0; f < 4; ++f)
#pragma unroll
      for (int g = 0; g < 4; ++g)
        acc[f][g] = __builtin_amdgcn_mfma_f32_16x16x32_bf16(av[f], bv[g], acc[f][g], 0, 0, 0);
    __syncthreads();
  }

  // C/D layout (m89-verified): col = lane&15, row = (lane>>4)*4 + reg
  const int cr = (l >> 4) * 4;
  const int cc = l & 15;
#pragma unroll
  for (int f = 0; f < 4; ++f) {
#pragma unroll
    for (int g = 0; g < 4; ++g) {
#pragma unroll
      for (int j = 0; j < 4; ++j) {
        long gr = mBase + wm * 64 + f * 16 + cr + j;
        long gc = nBase + wn * 64 + g * 16 + cc;
        float v = acc[f][g][j] + bias[gc];
        if (EPI == 0) {
          Cb[gr * N + gc] = f2bf(gelu_f(v));
        } else if (EPI == 1) {
          Cf[gr * N + gc] = v;
        } else {
          float wt = 0.f;
          if (idx0[gr] == expert) wt = w0[gr];
          else if (idx1[gr] == expert) wt = w1[gr];
          Cf[gr * N + gc] += wt * v;
        }
      }
    }
  }
}

__global__ void conv_x(const float* __restrict__ X, unsigned short* __restrict__ Xb) {
  int i = blockIdx.x * 256 + threadIdx.x;
  float4 v = reinterpret_cast<const float4*>(X)[i];
  union { unsigned short h[4]; uint2 u; } r;
  r.h[0] = f2bf(v.x); r.h[1] = f2bf(v.y); r.h[2] = f2bf(v.z); r.h[3] = f2bf(v.w);
  reinterpret_cast<uint2*>(Xb)[i] = r.u;
}

// out[n][k] = bf16(in[k][n]); batched via blockIdx.z
__global__ void transpose_conv(const float* __restrict__ in, unsigned short* __restrict__ out,
                               int K, int N, long long inStride, long long outStride) {
  __shared__ float tile[32][33];
  const float* ip = in + (long long)blockIdx.z * inStride;
  unsigned short* op = out + (long long)blockIdx.z * outStride;
  int k0 = blockIdx.y * 32, n0 = blockIdx.x * 32;
  int tx = threadIdx.x, ty = threadIdx.y;
#pragma unroll
  for (int j = 0; j < 32; j += 8)
    tile[ty + j][tx] = ip[(long long)(k0 + ty + j) * N + n0 + tx];
  __syncthreads();
#pragma unroll
  for (int j = 0; j < 32; j += 8)
    op[(long long)(n0 + ty + j) * K + k0 + tx] = f2bf(tile[tx][ty + j]);
}

__global__ void router_kernel(const float* __restrict__ X, const float* __restrict__ Wr,
                              int* __restrict__ idx0, int* __restrict__ idx1,
                              float* __restrict__ w0, float* __restrict__ w1,
                              float* __restrict__ auxAcc) {
  __shared__ float s_cnt[NE], s_wsum[NE];
  int t = threadIdx.x;
  if (t < NE) { s_cnt[t] = 0.f; s_wsum[t] = 0.f; }
  __syncthreads();
  int r = blockIdx.x * 256 + t;
  const float* x = X + (long)r * SD;
  float logit[NE];
#pragma unroll
  for (int e = 0; e < NE; e++) logit[e] = 0.f;
  for (int k = 0; k < SD; k++) {
    float xv = x[k];
    const float* wr = Wr + k * NE;  // uniform address -> scalar loads
#pragma unroll
    for (int e = 0; e < NE; e++) logit[e] += xv * wr[e];
  }
  float m = logit[0];
#pragma unroll
  for (int e = 1; e < NE; e++) m = fmaxf(m, logit[e]);
  // top-2 ON LOGITS (softmax is strictly monotone -> same ordering as probs;
  // avoids exp-rounding-induced reorders vs the fp32 reference).
  // ties -> lower index, matching lax.top_k.
  int i0 = 0; float q0 = logit[0];
#pragma unroll
  for (int e = 1; e < NE; e++) if (logit[e] > q0) { q0 = logit[e]; i0 = e; }
  int i1 = -1; float q1 = -3.4e38f;
#pragma unroll
  for (int e = 0; e < NE; e++) if (e != i0 && logit[e] > q1) { q1 = logit[e]; i1 = e; }
  float s = 0.f;
#pragma unroll
  for (int e = 0; e < NE; e++) s += __expf(logit[e] - m);
  float inv = 1.f / s;
  float W0 = __expf(q0 - m) * inv, W1 = __expf(q1 - m) * inv;
  idx0[r] = i0; idx1[r] = i1; w0[r] = W0; w1[r] = W1;
  atomicAdd(&s_cnt[i0], 1.f); atomicAdd(&s_cnt[i1], 1.f);
  atomicAdd(&s_wsum[i0], W0); atomicAdd(&s_wsum[i1], W1);
  __syncthreads();
  if (t < NE) { atomicAdd(&auxAcc[t], s_cnt[t]); atomicAdd(&auxAcc[NE + t], s_wsum[t]); }
}

__global__ void aux_finalize(const float* __restrict__ auxAcc, float* __restrict__ outAux) {
  float srt = 0.f;
  for (int e = 0; e < NE; e++) {
    float f = auxAcc[e] / (float)(RSEG * 2);
    float P = auxAcc[NE + e] / (float)RSEG;
    srt += f * P;
  }
  *outAux = (float)NE * srt;
}

extern "C" void kernel_launch(void* const* d_in, const int* in_sizes, int n_in,
                              void* d_out, int out_size, void* d_ws, size_t ws_size,
                              hipStream_t stream) {
  (void)in_sizes; (void)n_in; (void)out_size; (void)ws_size;
  const float* X   = (const float*)d_in[0];
  const float* Ws1 = (const float*)d_in[1];
  const float* bs1 = (const float*)d_in[2];
  const float* Ws2 = (const float*)d_in[3];
  const float* bs2 = (const float*)d_in[4];
  const float* Wr  = (const float*)d_in[5];
  const float* We1 = (const float*)d_in[6];
  const float* be1 = (const float*)d_in[7];
  const float* We2 = (const float*)d_in[8];
  const float* be2 = (const float*)d_in[9];
  float* out = (float*)d_out;

  char* p = (char*)d_ws;
  auto alloc = [&](size_t bytes) -> char* {
    char* q = p; p += (bytes + 511) & ~(size_t)511; return q;
  };
  unsigned short* Xb   = (unsigned short*)alloc((size_t)TOK * DIMC * 2);
  unsigned short* Ws1T = (unsigned short*)alloc((size_t)HSH * DIMC * 2);
  unsigned short* Ws2T = (unsigned short*)alloc((size_t)DIMC * HSH * 2);
  unsigned short* We1T = (unsigned short*)alloc((size_t)NE * HR * SD * 2);
  unsigned short* We2T = (unsigned short*)alloc((size_t)NE * SD * HR * 2);
  unsigned short* H1b  = (unsigned short*)alloc((size_t)TOK * HSH * 2);
  unsigned short* H2b  = (unsigned short*)alloc((size_t)RSEG * HR * 2);
  int*   idx0p = (int*)alloc((size_t)RSEG * 4);
  int*   idx1p = (int*)alloc((size_t)RSEG * 4);
  float* w0p   = (float*)alloc((size_t)RSEG * 4);
  float* w1p   = (float*)alloc((size_t)RSEG * 4);
  float* auxAcc = (float*)alloc(2 * NE * 4);

  hipMemsetAsync(auxAcc, 0, 2 * NE * 4, stream);

  conv_x<<<TOK * DIMC / 4 / 256, 256, 0, stream>>>(X, Xb);
  dim3 tb(32, 8);
  transpose_conv<<<dim3(HSH / 32, DIMC / 32, 1), tb, 0, stream>>>(Ws1, Ws1T, DIMC, HSH, 0, 0);
  transpose_conv<<<dim3(DIMC / 32, HSH / 32, 1), tb, 0, stream>>>(Ws2, Ws2T, HSH, DIMC, 0, 0);
  transpose_conv<<<dim3(HR / 32, SD / 32, NE), tb, 0, stream>>>(We1, We1T, SD, HR, (long long)SD * HR, (long long)HR * SD);
  transpose_conv<<<dim3(SD / 32, HR / 32, NE), tb, 0, stream>>>(We2, We2T, HR, SD, (long long)HR * SD, (long long)SD * HR);

  router_kernel<<<RSEG / 256, 256, 0, stream>>>(X, Wr, idx0p, idx1p, w0p, w1p, auxAcc);
  aux_finalize<<<1, 1, 0, stream>>>(auxAcc, out + (size_t)TOK * DIMC);

  // shared expert: out = (gelu(X@Ws1+bs1))@Ws2 + bs2   (writes ALL of out first)
  gemm_bt<0><<<dim3(HSH / BN, TOK / BM), 256, 0, stream>>>(
      Xb, Ws1T, bs1, nullptr, H1b, TOK, HSH, DIMC, 0, nullptr, nullptr, nullptr, nullptr);
  gemm_bt<1><<<dim3(DIMC / BN, TOK / BM), 256, 0, stream>>>(
      H1b, Ws2T, bs2, out, nullptr, TOK, DIMC, HSH, 0, nullptr, nullptr, nullptr, nullptr);

  // routed experts (dense masked combine): Xs = X viewed [RSEG, SD] contiguous;
  // routed output [RSEG, SD] is exactly contiguous with out.
  for (int e = 0; e < NE; e++) {
    gemm_bt<0><<<dim3(HR / BN, RSEG / BM), 256, 0, stream>>>(
        Xb, We1T + (size_t)e * HR * SD, be1 + e * HR, nullptr, H2b,
        RSEG, HR, SD, 0, nullptr, nullptr, nullptr, nullptr);
    gemm_bt<2><<<dim3(SD / BN, RSEG / BM), 256, 0, stream>>>(
        H2b, We2T + (size_t)e * SD * HR, be2 + e * SD, out, nullptr,
        RSEG, SD, HR, e, idx0p, idx1p, w0p, w1p);
  }
}

// Round 4
// 584.081 us; speedup vs baseline: 2.1630x; 2.1630x over previous
//
#include <hip/hip_runtime.h>
#include <stdint.h>

#define DIMC 1024
#define TOK  4096      // B*T
#define SEGN 8
#define SD   128
#define NE   16
#define RSEG 32768     // TOK*SEGN
#define HSH  4096
#define HR   512

#define BM 128
#define BN 128
#define BK 32

#define MAXT   528     // max routed tiles: 65536/128 + 16
#define MAXPAD (MAXT * BM)

using bf16x8 = __attribute__((ext_vector_type(8))) __bf16;
using f32x4  = __attribute__((ext_vector_type(4))) float;

__device__ __forceinline__ unsigned short f2bf(float f) {
  unsigned int x = __builtin_bit_cast(unsigned int, f);
  unsigned int r = (x + 0x7fffu + ((x >> 16) & 1u)) >> 16;
  return (unsigned short)r;
}

__device__ __forceinline__ float gelu_f(float x) {
  // jax.nn.gelu approximate=True == x * sigmoid(1.5957691(x+0.044715x^3))
  float u2 = -1.5957691216057308f * (x + 0.044715f * x * x * x);
  return x / (1.f + __expf(u2));
}

#define GLDS(gp, lp) __builtin_amdgcn_global_load_lds( \
    (const __attribute__((address_space(1))) void*)(gp), \
    (__attribute__((address_space(3))) void*)(lp), 16, 0, 0)

// C[M,N] = A[M,K] @ BT[N,K]^T  (bf16 in, fp32 accum)
// EPI 0: Cb[gr*N+gc] = bf16(gelu(acc+bias))        (dense or sparse-bucket out)
// EPI 1: Cf[gr*N+gc] = acc+bias
// EPI 3: ri=perm[gr]; if(ri>=0) atomicAdd(&Cf[ri*N+gc], wgt[gr]*(acc+bias))
// SPARSE: blockIdx.y indexes tile table; A rows via perm (EPI0) or bucket-dense (EPI3)
template <int EPI, bool SWZ, bool SPARSE>
__global__ __launch_bounds__(256) void gemm_bt(
    const unsigned short* __restrict__ A,
    const unsigned short* __restrict__ BT,
    const float* __restrict__ bias,
    float* __restrict__ Cf,
    unsigned short* __restrict__ Cb,
    int N, int K,
    const int* __restrict__ tileE, const int* __restrict__ tileR,
    const int* __restrict__ perm, const float* __restrict__ wgt,
    long btStride, int biasStride)
{
  __shared__ unsigned short As[BM * BK];
  __shared__ unsigned short Bs[BN * BK];
  const int t = threadIdx.x;
  const int w = t >> 6, l = t & 63;

  int bx = blockIdx.x, by = blockIdx.y;
  if (SWZ) {
    // bijective XCD chunking (m204): blocks resident on one XCD get a
    // contiguous run of work ids -> A-panel reuse in that XCD's L2.
    int gx = gridDim.x;
    int nwg = gx * gridDim.y;
    int flat = by * gx + bx;
    int q = nwg >> 3, r0 = nwg & 7;
    int xcd = flat & 7, j = flat >> 3;
    flat = (xcd < r0 ? xcd * (q + 1) : r0 * (q + 1) + (xcd - r0) * q) + j;
    bx = flat % gx; by = flat / gx;
  }

  long mBase;
  if (SPARSE) {
    int te = tileE[by];
    if (te < 0) return;                 // uniform: whole block exits
    mBase = tileR[by];
    BT += (long)te * btStride;
    bias += (long)te * biasStride;
  } else {
    mBase = (long)by * BM;
  }
  const long nBase = (long)bx * BN;
  const int wm = w >> 1, wn = w & 1;

  // staging: wave w rows [16w,16w+16) and [64+16w,...); lane l: row +(l>>2), 16B chunk (l&3)
  const int rowc = w * 16 + (l >> 2);
  const int colE = (l & 3) * 8;
  const unsigned short *gA0, *gA1;
  if (SPARSE && EPI == 0) {
    int r0 = perm[mBase + rowc];
    int r1 = perm[mBase + 64 + rowc];
    gA0 = A + (long)(r0 < 0 ? 0 : r0) * K + colE;   // pad rows -> row 0 (discarded later)
    gA1 = A + (long)(r1 < 0 ? 0 : r1) * K + colE;
  } else {
    gA0 = A + (mBase + rowc) * (long)K + colE;
    gA1 = A + (mBase + 64 + rowc) * (long)K + colE;
  }
  const unsigned short* gB0 = BT + (nBase + rowc) * (long)K + colE;
  const unsigned short* gB1 = BT + (nBase + 64 + rowc) * (long)K + colE;
  unsigned short* lA0 = &As[(w * 16) * BK];
  unsigned short* lA1 = &As[(64 + w * 16) * BK];
  unsigned short* lB0 = &Bs[(w * 16) * BK];
  unsigned short* lB1 = &Bs[(64 + w * 16) * BK];

  f32x4 acc[4][4] = {};

  const int ar = l & 15;
  const int ak = (l >> 4) * 8;

  for (int kt = 0; kt < K; kt += BK) {
    GLDS(gA0 + kt, lA0);
    GLDS(gA1 + kt, lA1);
    GLDS(gB0 + kt, lB0);
    GLDS(gB1 + kt, lB1);
    __syncthreads();
    bf16x8 av[4], bv[4];
#pragma unroll
    for (int f = 0; f < 4; ++f)
      av[f] = *(const bf16x8*)&As[(wm * 64 + f * 16 + ar) * BK + ak];
#pragma unroll
    for (int g = 0; g < 4; ++g)
      bv[g] = *(const bf16x8*)&Bs[(wn * 64 + g * 16 + ar) * BK + ak];
#pragma unroll
    for (int f = 0; f < 4; ++f)
#pragma unroll
      for (int g = 0; g < 4; ++g)
        acc[f][g] = __builtin_amdgcn_mfma_f32_16x16x32_bf16(av[f], bv[g], acc[f][g], 0, 0, 0);
    __syncthreads();
  }

  // C/D layout (m89): col = lane&15, row = (lane>>4)*4 + reg
  const int cr = (l >> 4) * 4;
  const int cc = l & 15;
#pragma unroll
  for (int f = 0; f < 4; ++f) {
#pragma unroll
    for (int j = 0; j < 4; ++j) {
      long gr = mBase + wm * 64 + f * 16 + cr + j;
      int ri = 0;
      float wv = 0.f;
      if (EPI == 3) {
        ri = perm[gr];
        wv = (ri >= 0) ? wgt[gr] : 0.f;
      }
#pragma unroll
      for (int g = 0; g < 4; ++g) {
        long gc = nBase + wn * 64 + g * 16 + cc;
        float v = acc[f][g][j] + bias[gc];
        if (EPI == 0) {
          Cb[gr * N + gc] = f2bf(gelu_f(v));
        } else if (EPI == 1) {
          Cf[gr * N + gc] = v;
        } else {
          if (ri >= 0) atomicAdd(&Cf[(long)ri * N + gc], wv * v);
        }
      }
    }
  }
}

__global__ void conv_x(const float* __restrict__ X, unsigned short* __restrict__ Xb) {
  int i = blockIdx.x * 256 + threadIdx.x;
  float4 v = reinterpret_cast<const float4*>(X)[i];
  union { unsigned short h[4]; uint2 u; } r;
  r.h[0] = f2bf(v.x); r.h[1] = f2bf(v.y); r.h[2] = f2bf(v.z); r.h[3] = f2bf(v.w);
  reinterpret_cast<uint2*>(Xb)[i] = r.u;
}

// out[n][k] = bf16(in[k][n]); batched via blockIdx.z
__global__ void transpose_conv(const float* __restrict__ in, unsigned short* __restrict__ out,
                               int K, int N, long long inStride, long long outStride) {
  __shared__ float tile[32][33];
  const float* ip = in + (long long)blockIdx.z * inStride;
  unsigned short* op = out + (long long)blockIdx.z * outStride;
  int k0 = blockIdx.y * 32, n0 = blockIdx.x * 32;
  int tx = threadIdx.x, ty = threadIdx.y;
#pragma unroll
  for (int j = 0; j < 32; j += 8)
    tile[ty + j][tx] = ip[(long long)(k0 + ty + j) * N + n0 + tx];
  __syncthreads();
#pragma unroll
  for (int j = 0; j < 32; j += 8)
    op[(long long)(n0 + ty + j) * K + k0 + tx] = f2bf(tile[tx][ty + j]);
}

__global__ void router_kernel(const float* __restrict__ X, const float* __restrict__ Wr,
                              int* __restrict__ idx0, int* __restrict__ idx1,
                              float* __restrict__ w0, float* __restrict__ w1,
                              unsigned int* __restrict__ cntI,
                              float* __restrict__ wsum) {
  __shared__ unsigned int s_cnt[NE];
  __shared__ float s_wsum[NE];
  int t = threadIdx.x;
  if (t < NE) { s_cnt[t] = 0u; s_wsum[t] = 0.f; }
  __syncthreads();
  int r = blockIdx.x * 256 + t;
  const float* x = X + (long)r * SD;
  float logit[NE];
#pragma unroll
  for (int e = 0; e < NE; e++) logit[e] = 0.f;
  for (int k = 0; k < SD; k++) {
    float xv = x[k];
    const float* wr = Wr + k * NE;
#pragma unroll
    for (int e = 0; e < NE; e++) logit[e] += xv * wr[e];
  }
  float m = logit[0];
#pragma unroll
  for (int e = 1; e < NE; e++) m = fmaxf(m, logit[e]);
  // top-2 on raw fp32 logits (softmax monotone => reference ordering; strict > => lower idx on tie)
  int i0 = 0; float q0 = logit[0];
#pragma unroll
  for (int e = 1; e < NE; e++) if (logit[e] > q0) { q0 = logit[e]; i0 = e; }
  int i1 = -1; float q1 = -3.4e38f;
#pragma unroll
  for (int e = 0; e < NE; e++) if (e != i0 && logit[e] > q1) { q1 = logit[e]; i1 = e; }
  float s = 0.f;
#pragma unroll
  for (int e = 0; e < NE; e++) s += __expf(logit[e] - m);
  float inv = 1.f / s;
  float W0 = __expf(q0 - m) * inv, W1 = __expf(q1 - m) * inv;
  idx0[r] = i0; idx1[r] = i1; w0[r] = W0; w1[r] = W1;
  atomicAdd(&s_cnt[i0], 1u); atomicAdd(&s_cnt[i1], 1u);
  atomicAdd(&s_wsum[i0], W0); atomicAdd(&s_wsum[i1], W1);
  __syncthreads();
  if (t < NE) { atomicAdd(&cntI[t], s_cnt[t]); atomicAdd(&wsum[t], s_wsum[t]); }
}

// single-thread: padded CSR offsets + tile table (<=528 tiles)
__global__ void build_tiles(const unsigned int* __restrict__ cntI,
                            int* __restrict__ off, int* __restrict__ tileE,
                            int* __restrict__ tileR) {
  int o = 0, t = 0;
  for (int e = 0; e < NE; e++) {
    off[e] = o;
    int c = (int)cntI[e];
    int nt = (c + BM - 1) / BM;
    for (int k = 0; k < nt; k++) { tileE[t] = e; tileR[t] = o + k * BM; t++; }
    o += nt * BM;
  }
  for (; t < MAXT; t++) { tileE[t] = -1; tileR[t] = 0; }
}

__global__ void scatter_perm(const int* __restrict__ idx0, const int* __restrict__ idx1,
                             const float* __restrict__ w0, const float* __restrict__ w1,
                             const int* __restrict__ off, unsigned int* __restrict__ fill,
                             int* __restrict__ perm, float* __restrict__ wgt) {
  int r = blockIdx.x * 256 + threadIdx.x;
  int e0 = idx0[r];
  int loc0 = off[e0] + (int)atomicAdd(&fill[e0], 1u);
  perm[loc0] = r; wgt[loc0] = w0[r];
  int e1 = idx1[r];
  int loc1 = off[e1] + (int)atomicAdd(&fill[e1], 1u);
  perm[loc1] = r; wgt[loc1] = w1[r];
}

__global__ void aux_finalize(const unsigned int* __restrict__ cntI,
                             const float* __restrict__ wsum, float* __restrict__ outAux) {
  float srt = 0.f;
  for (int e = 0; e < NE; e++) {
    float f = (float)cntI[e] / (float)(RSEG * 2);
    float P = wsum[e] / (float)RSEG;
    srt += f * P;
  }
  *outAux = (float)NE * srt;
}

extern "C" void kernel_launch(void* const* d_in, const int* in_sizes, int n_in,
                              void* d_out, int out_size, void* d_ws, size_t ws_size,
                              hipStream_t stream) {
  (void)in_sizes; (void)n_in; (void)out_size; (void)ws_size;
  const float* X   = (const float*)d_in[0];
  const float* Ws1 = (const float*)d_in[1];
  const float* bs1 = (const float*)d_in[2];
  const float* Ws2 = (const float*)d_in[3];
  const float* bs2 = (const float*)d_in[4];
  const float* Wr  = (const float*)d_in[5];
  const float* We1 = (const float*)d_in[6];
  const float* be1 = (const float*)d_in[7];
  const float* We2 = (const float*)d_in[8];
  const float* be2 = (const float*)d_in[9];
  float* out = (float*)d_out;

  char* p = (char*)d_ws;
  auto alloc = [&](size_t bytes) -> char* {
    char* q = p; p += (bytes + 511) & ~(size_t)511; return q;
  };
  unsigned short* Xb = (unsigned short*)alloc((size_t)TOK * DIMC * 2);     // 8.4 MB
  // region1: shared-phase {Ws1T|Ws2T|H1b} (50.3 MB), later aliased by Hg (69.2 MB)
  char* region1 = alloc((size_t)MAXPAD * HR * 2);
  unsigned short* Hg   = (unsigned short*)region1;
  unsigned short* Ws1T = (unsigned short*)region1;
  unsigned short* Ws2T = (unsigned short*)(region1 + (size_t)HSH * DIMC * 2);
  unsigned short* H1b  = (unsigned short*)(region1 + (size_t)2 * HSH * DIMC * 2);
  unsigned short* We1T = (unsigned short*)alloc((size_t)NE * HR * SD * 2); // 2.1 MB
  unsigned short* We2T = (unsigned short*)alloc((size_t)NE * SD * HR * 2); // 2.1 MB
  int*   idx0p = (int*)alloc((size_t)RSEG * 4);
  int*   idx1p = (int*)alloc((size_t)RSEG * 4);
  float* w0p   = (float*)alloc((size_t)RSEG * 4);
  float* w1p   = (float*)alloc((size_t)RSEG * 4);
  int*   permp = (int*)alloc((size_t)MAXPAD * 4);
  float* wgtp  = (float*)alloc((size_t)MAXPAD * 4);
  unsigned int* cntI = (unsigned int*)alloc(NE * 4);
  unsigned int* fill = (unsigned int*)alloc(NE * 4);
  int*   offp  = (int*)alloc(NE * 4);
  int*   tileE = (int*)alloc(MAXT * 4);
  int*   tileR = (int*)alloc(MAXT * 4);
  float* wsum  = (float*)alloc(NE * 4);

  hipMemsetAsync(cntI, 0, NE * 4, stream);
  hipMemsetAsync(fill, 0, NE * 4, stream);
  hipMemsetAsync(wsum, 0, NE * 4, stream);
  hipMemsetAsync(permp, 0xFF, (size_t)MAXPAD * 4, stream);   // perm = -1 (pad marker)

  conv_x<<<TOK * DIMC / 4 / 256, 256, 0, stream>>>(X, Xb);
  dim3 tb(32, 8);
  transpose_conv<<<dim3(HSH / 32, DIMC / 32, 1), tb, 0, stream>>>(Ws1, Ws1T, DIMC, HSH, 0, 0);
  transpose_conv<<<dim3(DIMC / 32, HSH / 32, 1), tb, 0, stream>>>(Ws2, Ws2T, HSH, DIMC, 0, 0);
  transpose_conv<<<dim3(HR / 32, SD / 32, NE), tb, 0, stream>>>(We1, We1T, SD, HR, (long long)SD * HR, (long long)HR * SD);
  transpose_conv<<<dim3(SD / 32, HR / 32, NE), tb, 0, stream>>>(We2, We2T, HR, SD, (long long)HR * SD, (long long)SD * HR);

  router_kernel<<<RSEG / 256, 256, 0, stream>>>(X, Wr, idx0p, idx1p, w0p, w1p, cntI, wsum);
  build_tiles<<<1, 1, 0, stream>>>(cntI, offp, tileE, tileR);
  scatter_perm<<<RSEG / 256, 256, 0, stream>>>(idx0p, idx1p, w0p, w1p, offp, fill, permp, wgtp);
  aux_finalize<<<1, 1, 0, stream>>>(cntI, wsum, out + (size_t)TOK * DIMC);

  // shared expert (writes all of out; must precede routed atomics)
  gemm_bt<0, true, false><<<dim3(HSH / BN, TOK / BM), 256, 0, stream>>>(
      Xb, Ws1T, bs1, nullptr, H1b, HSH, DIMC, nullptr, nullptr, nullptr, nullptr, 0, 0);
  gemm_bt<1, true, false><<<dim3(DIMC / BN, TOK / BM), 256, 0, stream>>>(
      H1b, Ws2T, bs2, out, nullptr, DIMC, HSH, nullptr, nullptr, nullptr, nullptr, 0, 0);

  // routed experts, sparse CSR buckets (Hg aliases shared-phase buffers - ordered after)
  gemm_bt<0, false, true><<<dim3(HR / BN, MAXT), 256, 0, stream>>>(
      Xb, We1T, be1, nullptr, Hg, HR, SD, tileE, tileR, permp, wgtp, (long)HR * SD, HR);
  gemm_bt<3, false, true><<<dim3(SD / BN, MAXT), 256, 0, stream>>>(
      Hg, We2T, be2, out, nullptr, SD, HR, tileE, tileR, permp, wgtp, (long)SD * HR, SD);
}

// Round 5
// 407.987 us; speedup vs baseline: 3.0966x; 1.4316x over previous
//
#include <hip/hip_runtime.h>
#include <stdint.h>

#define DIMC 1024
#define TOK  4096      // B*T
#define SEGN 8
#define SD   128
#define NE   16
#define RSEG 32768     // TOK*SEGN
#define HSH  4096
#define HR   512

#define BM 128
#define BN 128
#define BK 32

#define MAXT   528     // max routed tiles: 65536/128 + 16
#define MAXPAD (MAXT * BM)

using bf16x8 = __attribute__((ext_vector_type(8))) __bf16;
using f32x4  = __attribute__((ext_vector_type(4))) float;

__device__ __forceinline__ unsigned short f2bf(float f) {
  unsigned int x = __builtin_bit_cast(unsigned int, f);
  unsigned int r = (x + 0x7fffu + ((x >> 16) & 1u)) >> 16;
  return (unsigned short)r;
}

__device__ __forceinline__ float gelu_f(float x) {
  // jax.nn.gelu approximate=True == x * sigmoid(1.5957691(x+0.044715x^3))
  float u2 = -1.5957691216057308f * (x + 0.044715f * x * x * x);
  return x / (1.f + __expf(u2));
}

#define GLDS(gp, lp) __builtin_amdgcn_global_load_lds( \
    (const __attribute__((address_space(1))) void*)(gp), \
    (__attribute__((address_space(3))) void*)(lp), 16, 0, 0)

// C[M,N] = A[M,K] @ BT[N,K]^T  (bf16 in, fp32 accum)
// EPI 0: Cb[gr*N+gc] = bf16(gelu(acc+bias))        (dense or sparse-bucket out)
// EPI 1: Cf[gr*N+gc] = acc+bias
// EPI 3: ri=perm[gr]; if(ri>=0) atomicAdd(&Cf[ri*N+gc], wgt[gr]*(acc+bias))
// SPARSE: blockIdx.y indexes tile table; A rows via perm (EPI0) or bucket-dense (EPI3)
template <int EPI, bool SWZ, bool SPARSE>
__global__ __launch_bounds__(256) void gemm_bt(
    const unsigned short* __restrict__ A,
    const unsigned short* __restrict__ BT,
    const float* __restrict__ bias,
    float* __restrict__ Cf,
    unsigned short* __restrict__ Cb,
    int N, int K,
    const int* __restrict__ tileE, const int* __restrict__ tileR,
    const int* __restrict__ perm, const float* __restrict__ wgt,
    long btStride, int biasStride)
{
  __shared__ unsigned short As[BM * BK];
  __shared__ unsigned short Bs[BN * BK];
  const int t = threadIdx.x;
  const int w = t >> 6, l = t & 63;

  int bx = blockIdx.x, by = blockIdx.y;
  if (SWZ) {
    // bijective XCD chunking (m204): blocks resident on one XCD get a
    // contiguous run of work ids -> A-panel reuse in that XCD's L2.
    int gx = gridDim.x;
    int nwg = gx * gridDim.y;
    int flat = by * gx + bx;
    int q = nwg >> 3, r0 = nwg & 7;
    int xcd = flat & 7, j = flat >> 3;
    flat = (xcd < r0 ? xcd * (q + 1) : r0 * (q + 1) + (xcd - r0) * q) + j;
    bx = flat % gx; by = flat / gx;
  }

  long mBase;
  if (SPARSE) {
    int te = tileE[by];
    if (te < 0) return;                 // uniform: whole block exits
    mBase = tileR[by];
    BT += (long)te * btStride;
    bias += (long)te * biasStride;
  } else {
    mBase = (long)by * BM;
  }
  const long nBase = (long)bx * BN;
  const int wm = w >> 1, wn = w & 1;

  // staging: wave w rows [16w,16w+16) and [64+16w,...); lane l: row +(l>>2), 16B chunk (l&3)
  const int rowc = w * 16 + (l >> 2);
  const int colE = (l & 3) * 8;
  const unsigned short *gA0, *gA1;
  if (SPARSE && EPI == 0) {
    int r0 = perm[mBase + rowc];
    int r1 = perm[mBase + 64 + rowc];
    gA0 = A + (long)(r0 < 0 ? 0 : r0) * K + colE;   // pad rows -> row 0 (discarded later)
    gA1 = A + (long)(r1 < 0 ? 0 : r1) * K + colE;
  } else {
    gA0 = A + (mBase + rowc) * (long)K + colE;
    gA1 = A + (mBase + 64 + rowc) * (long)K + colE;
  }
  const unsigned short* gB0 = BT + (nBase + rowc) * (long)K + colE;
  const unsigned short* gB1 = BT + (nBase + 64 + rowc) * (long)K + colE;
  unsigned short* lA0 = &As[(w * 16) * BK];
  unsigned short* lA1 = &As[(64 + w * 16) * BK];
  unsigned short* lB0 = &Bs[(w * 16) * BK];
  unsigned short* lB1 = &Bs[(64 + w * 16) * BK];

  f32x4 acc[4][4] = {};

  const int ar = l & 15;
  const int ak = (l >> 4) * 8;

  for (int kt = 0; kt < K; kt += BK) {
    GLDS(gA0 + kt, lA0);
    GLDS(gA1 + kt, lA1);
    GLDS(gB0 + kt, lB0);
    GLDS(gB1 + kt, lB1);
    __syncthreads();
    bf16x8 av[4], bv[4];
#pragma unroll
    for (int f = 0; f < 4; ++f)
      av[f] = *(const bf16x8*)&As[(wm * 64 + f * 16 + ar) * BK + ak];
#pragma unroll
    for (int g = 0; g < 4; ++g)
      bv[g] = *(const bf16x8*)&Bs[(wn * 64 + g * 16 + ar) * BK + ak];
#pragma unroll
    for (int f = 0; f < 4; ++f)
#pragma unroll
      for (int g = 0; g < 4; ++g)
        acc[f][g] = __builtin_amdgcn_mfma_f32_16x16x32_bf16(av[f], bv[g], acc[f][g], 0, 0, 0);
    __syncthreads();
  }

  // C/D layout (m89): col = lane&15, row = (lane>>4)*4 + reg
  const int cr = (l >> 4) * 4;
  const int cc = l & 15;
#pragma unroll
  for (int f = 0; f < 4; ++f) {
#pragma unroll
    for (int j = 0; j < 4; ++j) {
      long gr = mBase + wm * 64 + f * 16 + cr + j;
      int ri = 0;
      float wv = 0.f;
      if (EPI == 3) {
        ri = perm[gr];
        wv = (ri >= 0) ? wgt[gr] : 0.f;
      }
#pragma unroll
      for (int g = 0; g < 4; ++g) {
        long gc = nBase + wn * 64 + g * 16 + cc;
        float v = acc[f][g][j] + bias[gc];
        if (EPI == 0) {
          Cb[gr * N + gc] = f2bf(gelu_f(v));
        } else if (EPI == 1) {
          Cf[gr * N + gc] = v;
        } else {
          if (ri >= 0) atomicAdd(&Cf[(long)ri * N + gc], wv * v);
        }
      }
    }
  }
}

__global__ void conv_x(const float* __restrict__ X, unsigned short* __restrict__ Xb) {
  int i = blockIdx.x * 256 + threadIdx.x;
  float4 v = reinterpret_cast<const float4*>(X)[i];
  union { unsigned short h[4]; uint2 u; } r;
  r.h[0] = f2bf(v.x); r.h[1] = f2bf(v.y); r.h[2] = f2bf(v.z); r.h[3] = f2bf(v.w);
  reinterpret_cast<uint2*>(Xb)[i] = r.u;
}

// out[n][k] = bf16(in[k][n]); batched via blockIdx.z
__global__ void transpose_conv(const float* __restrict__ in, unsigned short* __restrict__ out,
                               int K, int N, long long inStride, long long outStride) {
  __shared__ float tile[32][33];
  const float* ip = in + (long long)blockIdx.z * inStride;
  unsigned short* op = out + (long long)blockIdx.z * outStride;
  int k0 = blockIdx.y * 32, n0 = blockIdx.x * 32;
  int tx = threadIdx.x, ty = threadIdx.y;
#pragma unroll
  for (int j = 0; j < 32; j += 8)
    tile[ty + j][tx] = ip[(long long)(k0 + ty + j) * N + n0 + tx];
  __syncthreads();
#pragma unroll
  for (int j = 0; j < 32; j += 8)
    op[(long long)(n0 + ty + j) * K + k0 + tx] = f2bf(tile[tx][ty + j]);
}

__global__ void router_kernel(const float* __restrict__ X, const float* __restrict__ Wr,
                              int* __restrict__ idx0, int* __restrict__ idx1,
                              float* __restrict__ w0, float* __restrict__ w1,
                              unsigned int* __restrict__ cntI,
                              float* __restrict__ wsum) {
  __shared__ unsigned int s_cnt[NE];
  __shared__ float s_wsum[NE];
  int t = threadIdx.x;
  if (t < NE) { s_cnt[t] = 0u; s_wsum[t] = 0.f; }
  __syncthreads();
  int r = blockIdx.x * 256 + t;
  const float* x = X + (long)r * SD;
  float logit[NE];
#pragma unroll
  for (int e = 0; e < NE; e++) logit[e] = 0.f;
  for (int k = 0; k < SD; k++) {
    float xv = x[k];
    const float* wr = Wr + k * NE;
#pragma unroll
    for (int e = 0; e < NE; e++) logit[e] += xv * wr[e];
  }
  float m = logit[0];
#pragma unroll
  for (int e = 1; e < NE; e++) m = fmaxf(m, logit[e]);
  // top-2 on raw fp32 logits (softmax monotone => reference ordering; strict > => lower idx on tie)
  int i0 = 0; float q0 = logit[0];
#pragma unroll
  for (int e = 1; e < NE; e++) if (logit[e] > q0) { q0 = logit[e]; i0 = e; }
  int i1 = -1; float q1 = -3.4e38f;
#pragma unroll
  for (int e = 0; e < NE; e++) if (e != i0 && logit[e] > q1) { q1 = logit[e]; i1 = e; }
  float s = 0.f;
#pragma unroll
  for (int e = 0; e < NE; e++) s += __expf(logit[e] - m);
  float inv = 1.f / s;
  float W0 = __expf(q0 - m) * inv, W1 = __expf(q1 - m) * inv;
  idx0[r] = i0; idx1[r] = i1; w0[r] = W0; w1[r] = W1;
  atomicAdd(&s_cnt[i0], 1u); atomicAdd(&s_cnt[i1], 1u);
  atomicAdd(&s_wsum[i0], W0); atomicAdd(&s_wsum[i1], W1);
  __syncthreads();
  if (t < NE) { atomicAdd(&cntI[t], s_cnt[t]); atomicAdd(&wsum[t], s_wsum[t]); }
}

// single-thread: padded CSR offsets + tile table (<=528 tiles)
__global__ void build_tiles(const unsigned int* __restrict__ cntI,
                            int* __restrict__ off, int* __restrict__ tileE,
                            int* __restrict__ tileR) {
  int o = 0, t = 0;
  for (int e = 0; e < NE; e++) {
    off[e] = o;
    int c = (int)cntI[e];
    int nt = (c + BM - 1) / BM;
    for (int k = 0; k < nt; k++) { tileE[t] = e; tileR[t] = o + k * BM; t++; }
    o += nt * BM;
  }
  for (; t < MAXT; t++) { tileE[t] = -1; tileR[t] = 0; }
}

// hierarchical rank allocation: LDS ranks per block, ONE global atomic per
// (block, expert) to reserve a range (G12: 65536 contended atomics -> 2048).
__global__ void scatter_perm(const int* __restrict__ idx0, const int* __restrict__ idx1,
                             const float* __restrict__ w0, const float* __restrict__ w1,
                             const int* __restrict__ off, unsigned int* __restrict__ fill,
                             int* __restrict__ perm, float* __restrict__ wgt) {
  __shared__ unsigned int s_cnt[NE];
  __shared__ unsigned int s_base[NE];
  int t = threadIdx.x;
  if (t < NE) s_cnt[t] = 0u;
  __syncthreads();
  int r = blockIdx.x * 256 + t;
  int e0 = idx0[r], e1 = idx1[r];
  unsigned int rk0 = atomicAdd(&s_cnt[e0], 1u);
  unsigned int rk1 = atomicAdd(&s_cnt[e1], 1u);
  __syncthreads();
  if (t < NE) s_base[t] = atomicAdd(&fill[t], s_cnt[t]);
  __syncthreads();
  int loc0 = off[e0] + (int)(s_base[e0] + rk0);
  perm[loc0] = r; wgt[loc0] = w0[r];
  int loc1 = off[e1] + (int)(s_base[e1] + rk1);
  perm[loc1] = r; wgt[loc1] = w1[r];
}

__global__ void aux_finalize(const unsigned int* __restrict__ cntI,
                             const float* __restrict__ wsum, float* __restrict__ outAux) {
  float srt = 0.f;
  for (int e = 0; e < NE; e++) {
    float f = (float)cntI[e] / (float)(RSEG * 2);
    float P = wsum[e] / (float)RSEG;
    srt += f * P;
  }
  *outAux = (float)NE * srt;
}

extern "C" void kernel_launch(void* const* d_in, const int* in_sizes, int n_in,
                              void* d_out, int out_size, void* d_ws, size_t ws_size,
                              hipStream_t stream) {
  (void)in_sizes; (void)n_in; (void)out_size; (void)ws_size;
  const float* X   = (const float*)d_in[0];
  const float* Ws1 = (const float*)d_in[1];
  const float* bs1 = (const float*)d_in[2];
  const float* Ws2 = (const float*)d_in[3];
  const float* bs2 = (const float*)d_in[4];
  const float* Wr  = (const float*)d_in[5];
  const float* We1 = (const float*)d_in[6];
  const float* be1 = (const float*)d_in[7];
  const float* We2 = (const float*)d_in[8];
  const float* be2 = (const float*)d_in[9];
  float* out = (float*)d_out;

  char* p = (char*)d_ws;
  auto alloc = [&](size_t bytes) -> char* {
    char* q = p; p += (bytes + 511) & ~(size_t)511; return q;
  };
  unsigned short* Xb = (unsigned short*)alloc((size_t)TOK * DIMC * 2);     // 8.4 MB
  // region1: shared-phase {Ws1T|Ws2T|H1b} (50.3 MB), later aliased by Hg (69.2 MB)
  char* region1 = alloc((size_t)MAXPAD * HR * 2);
  unsigned short* Hg   = (unsigned short*)region1;
  unsigned short* Ws1T = (unsigned short*)region1;
  unsigned short* Ws2T = (unsigned short*)(region1 + (size_t)HSH * DIMC * 2);
  unsigned short* H1b  = (unsigned short*)(region1 + (size_t)2 * HSH * DIMC * 2);
  unsigned short* We1T = (unsigned short*)alloc((size_t)NE * HR * SD * 2); // 2.1 MB
  unsigned short* We2T = (unsigned short*)alloc((size_t)NE * SD * HR * 2); // 2.1 MB
  int*   idx0p = (int*)alloc((size_t)RSEG * 4);
  int*   idx1p = (int*)alloc((size_t)RSEG * 4);
  float* w0p   = (float*)alloc((size_t)RSEG * 4);
  float* w1p   = (float*)alloc((size_t)RSEG * 4);
  int*   permp = (int*)alloc((size_t)MAXPAD * 4);
  float* wgtp  = (float*)alloc((size_t)MAXPAD * 4);
  unsigned int* cntI = (unsigned int*)alloc(NE * 4);
  unsigned int* fill = (unsigned int*)alloc(NE * 4);
  int*   offp  = (int*)alloc(NE * 4);
  int*   tileE = (int*)alloc(MAXT * 4);
  int*   tileR = (int*)alloc(MAXT * 4);
  float* wsum  = (float*)alloc(NE * 4);

  hipMemsetAsync(cntI, 0, NE * 4, stream);
  hipMemsetAsync(fill, 0, NE * 4, stream);
  hipMemsetAsync(wsum, 0, NE * 4, stream);
  hipMemsetAsync(permp, 0xFF, (size_t)MAXPAD * 4, stream);   // perm = -1 (pad marker)

  conv_x<<<TOK * DIMC / 4 / 256, 256, 0, stream>>>(X, Xb);
  dim3 tb(32, 8);
  transpose_conv<<<dim3(HSH / 32, DIMC / 32, 1), tb, 0, stream>>>(Ws1, Ws1T, DIMC, HSH, 0, 0);
  transpose_conv<<<dim3(DIMC / 32, HSH / 32, 1), tb, 0, stream>>>(Ws2, Ws2T, HSH, DIMC, 0, 0);
  transpose_conv<<<dim3(HR / 32, SD / 32, NE), tb, 0, stream>>>(We1, We1T, SD, HR, (long long)SD * HR, (long long)HR * SD);
  transpose_conv<<<dim3(SD / 32, HR / 32, NE), tb, 0, stream>>>(We2, We2T, HR, SD, (long long)HR * SD, (long long)SD * HR);

  router_kernel<<<RSEG / 256, 256, 0, stream>>>(X, Wr, idx0p, idx1p, w0p, w1p, cntI, wsum);
  build_tiles<<<1, 1, 0, stream>>>(cntI, offp, tileE, tileR);
  scatter_perm<<<RSEG / 256, 256, 0, stream>>>(idx0p, idx1p, w0p, w1p, offp, fill, permp, wgtp);
  aux_finalize<<<1, 1, 0, stream>>>(cntI, wsum, out + (size_t)TOK * DIMC);

  // shared expert (writes all of out; must precede routed atomics)
  gemm_bt<0, true, false><<<dim3(HSH / BN, TOK / BM), 256, 0, stream>>>(
      Xb, Ws1T, bs1, nullptr, H1b, HSH, DIMC, nullptr, nullptr, nullptr, nullptr, 0, 0);
  gemm_bt<1, true, false><<<dim3(DIMC / BN, TOK / BM), 256, 0, stream>>>(
      H1b, Ws2T, bs2, out, nullptr, DIMC, HSH, nullptr, nullptr, nullptr, nullptr, 0, 0);

  // routed experts, sparse CSR buckets (Hg aliases shared-phase buffers - ordered after)
  gemm_bt<0, false, true><<<dim3(HR / BN, MAXT), 256, 0, stream>>>(
      Xb, We1T, be1, nullptr, Hg, HR, SD, tileE, tileR, permp, wgtp, (long)HR * SD, HR);
  gemm_bt<3, false, true><<<dim3(SD / BN, MAXT), 256, 0, stream>>>(
      Hg, We2T, be2, out, nullptr, SD, HR, tileE, tileR, permp, wgtp, (long)SD * HR, SD);
}